// Round 1
// baseline (8398.557 us; speedup 1.0000x reference)
//
#include <hip/hip_runtime.h>
#include <hip/hip_fp16.h>

#define B_ 32
#define S_ 2048
#define H_ 256

union UH { unsigned int u; __half2 h; };
__device__ __forceinline__ __half2 u2h(unsigned int u){ UH x; x.u = u; return x.h; }

__device__ __forceinline__ float fast_tanh(float x){
  // tanh(x) = 1 - 2/(exp(2x)+1); exact at +-inf, ~1e-7 rel err elsewhere
  float e = __expf(2.0f*x);
  return 1.0f - 2.0f/(e + 1.0f);
}

__device__ __forceinline__ float hsum8(__half2 a, __half2 b, __half2 c, __half2 d){
  float2 fa = __half22float2(a), fb = __half22float2(b);
  float2 fc = __half22float2(c), fd = __half22float2(d);
  return ((fa.x+fa.y)+(fb.x+fb.y)) + ((fc.x+fc.y)+(fd.x+fd.y));
}

// Pack fp32 [256][256] (k-major) into half2 [k2][j] with pair = (W[2k2][j], W[2k2+1][j])
__global__ void pack_w(const float* __restrict__ W, __half2* __restrict__ Wp){
  int idx = blockIdx.x*256 + threadIdx.x;        // 0..32767
  int k2 = idx >> 8, j = idx & 255;
  Wp[idx] = __floats2half2_rn(W[(2*k2)*256 + j], W[(2*k2+1)*256 + j]);
}

// Generic (M x 256) @ (256 x 256) + bias, rows r0..r0+31 per block.
// mode 0: Out[r*256+j]      (phase A: Z0[b][t][j], r = b*S+t)
// mode 1: Out[(b*S+t)*256+j] with r = t*32+b  (phase C: outputs from h_states[1] rows)
__global__ __launch_bounds__(256) void gemm256(
    const float* __restrict__ X, const __half2* __restrict__ Wp,
    const float* __restrict__ bias, float* __restrict__ Out, int mode)
{
  __shared__ __align__(16) __half2 xsh[32][128];
  const int j = threadIdx.x;
  const size_t r0 = (size_t)blockIdx.x * 32;

  for (int i = j; i < 32*128; i += 256){
    int rr = i >> 7, k2 = i & 127;
    const float* xs = X + (r0 + rr)*256 + 2*k2;
    xsh[rr][k2] = __floats2half2_rn(xs[0], xs[1]);
  }
  __half2 acc[32];
  #pragma unroll
  for (int r=0;r<32;r++) acc[r] = __floats2half2_rn(0.f,0.f);
  __syncthreads();

  for (int kc=0;kc<32;kc++){
    __half2 w0 = Wp[(kc*4+0)*256 + j];
    __half2 w1 = Wp[(kc*4+1)*256 + j];
    __half2 w2 = Wp[(kc*4+2)*256 + j];
    __half2 w3 = Wp[(kc*4+3)*256 + j];
    #pragma unroll
    for (int r=0;r<32;r++){
      uint4 xv = *reinterpret_cast<const uint4*>(&xsh[r][kc*4]);
      __half2 t0 = __hfma2(u2h(xv.x), w0, acc[r]);
      t0 = __hfma2(u2h(xv.y), w1, t0);
      t0 = __hfma2(u2h(xv.z), w2, t0);
      acc[r] = __hfma2(u2h(xv.w), w3, t0);
    }
  }
  float bj = bias[j];
  if (mode == 0){
    #pragma unroll
    for (int r=0;r<32;r++){
      float2 f = __half22float2(acc[r]);
      Out[(r0 + r)*256 + j] = bj + f.x + f.y;
    }
  } else {
    #pragma unroll
    for (int r=0;r<32;r++){
      size_t rr = r0 + r;
      size_t tt = rr >> 5, bb = rr & 31;
      float2 f = __half22float2(acc[r]);
      Out[(bb*(size_t)S_ + tt)*256 + j] = bj + f.x + f.y;
    }
  }
}

// Sequential scan: one workgroup per sample, 256 threads (thread j = column j).
// Recurrent weights live entirely in VGPRs (3 x 128 half2 = 384 VGPRs).
__global__ __launch_bounds__(256, 1) void rnn_seq(
    const __half2* __restrict__ Wp_hh0, const __half2* __restrict__ Wp_xh1,
    const __half2* __restrict__ Wp_hh1, const float* __restrict__ hprev,
    const float* __restrict__ b1, const float* __restrict__ Z0,
    float* __restrict__ hsbase, float* __restrict__ hf)
{
  const int b = blockIdx.x, j = threadIdx.x;
  __shared__ __align__(16) __half hA[2][256];
  __shared__ __align__(16) __half hB[2][256];

  __half2 w0[128], w1[128], w2[128];
  #pragma unroll
  for (int k=0;k<128;k++){
    w0[k] = Wp_hh0[k*256 + j];
    w1[k] = Wp_xh1[k*256 + j];
    w2[k] = Wp_hh1[k*256 + j];
  }
  const float b1j = b1[j];
  hA[0][j] = __float2half(hprev[b*256 + j]);
  hB[0][j] = __float2half(hprev[B_*H_ + b*256 + j]);

  const float* zp = Z0 + (size_t)b*S_*H_ + j;
  float zcur = zp[0];
  float* hs0 = hsbase + (size_t)b*H_ + j;
  float* hs1 = hsbase + (size_t)S_*B_*H_ + (size_t)b*H_ + j;
  __syncthreads();

  int cur = 0;
  float h0n = 0.f, h1n = 0.f;
  for (int t=0; t<S_; t++){
    float znext = zp[(size_t)(t+1 < S_ ? t+1 : t)*H_];   // prefetch next step's z

    // layer 0: h0 = tanh(z + h0_prev @ W_hh0)
    __half2 s0 = __floats2half2_rn(0.f,0.f), s1=s0, s2=s0, s3=s0;
    const uint4* hv = reinterpret_cast<const uint4*>(&hA[cur][0]);
    #pragma unroll
    for (int c=0;c<32;c++){
      uint4 x4 = hv[c];
      s0 = __hfma2(u2h(x4.x), w0[4*c+0], s0);
      s1 = __hfma2(u2h(x4.y), w0[4*c+1], s1);
      s2 = __hfma2(u2h(x4.z), w0[4*c+2], s2);
      s3 = __hfma2(u2h(x4.w), w0[4*c+3], s3);
    }
    h0n = fast_tanh(zcur + hsum8(s0,s1,s2,s3));
    hs0[(size_t)t*B_*H_] = h0n;
    hA[cur^1][j] = __float2half(h0n);
    __syncthreads();

    // layer 1: h1 = tanh(h0_new @ W_xh1 + h1_prev @ W_hh1 + b1)
    s0 = __floats2half2_rn(0.f,0.f); s1=s0; s2=s0; s3=s0;
    const uint4* hv1 = reinterpret_cast<const uint4*>(&hA[cur^1][0]);
    const uint4* hv2 = reinterpret_cast<const uint4*>(&hB[cur][0]);
    #pragma unroll
    for (int c=0;c<32;c++){
      uint4 x4 = hv1[c];
      s0 = __hfma2(u2h(x4.x), w1[4*c+0], s0);
      s1 = __hfma2(u2h(x4.y), w1[4*c+1], s1);
      s2 = __hfma2(u2h(x4.z), w1[4*c+2], s2);
      s3 = __hfma2(u2h(x4.w), w1[4*c+3], s3);
    }
    #pragma unroll
    for (int c=0;c<32;c++){
      uint4 x4 = hv2[c];
      s0 = __hfma2(u2h(x4.x), w2[4*c+0], s0);
      s1 = __hfma2(u2h(x4.y), w2[4*c+1], s1);
      s2 = __hfma2(u2h(x4.z), w2[4*c+2], s2);
      s3 = __hfma2(u2h(x4.w), w2[4*c+3], s3);
    }
    h1n = fast_tanh(b1j + hsum8(s0,s1,s2,s3));
    hs1[(size_t)t*B_*H_] = h1n;
    hB[cur^1][j] = __float2half(h1n);
    zcur = znext;
    __syncthreads();
    cur ^= 1;
  }
  hf[(size_t)b*H_ + j] = h0n;
  hf[(size_t)B_*H_ + (size_t)b*H_ + j] = h1n;
}

extern "C" void kernel_launch(void* const* d_in, const int* in_sizes, int n_in,
                              void* d_out, int out_size, void* d_ws, size_t ws_size,
                              hipStream_t stream)
{
  const float* x     = (const float*)d_in[0];
  const float* hprev = (const float*)d_in[1];
  const float* Wxh0  = (const float*)d_in[2];
  const float* Whh0  = (const float*)d_in[3];
  const float* bh0   = (const float*)d_in[4];
  const float* Wxh1  = (const float*)d_in[5];
  const float* Whh1  = (const float*)d_in[6];
  const float* bh1   = (const float*)d_in[7];
  const float* Why   = (const float*)d_in[8];
  const float* by    = (const float*)d_in[9];
  float* out = (float*)d_out;

  const size_t N_Y  = (size_t)B_*S_*H_;    // outputs region: 16,777,216 floats
  const size_t N_HS = (size_t)2*S_*B_*H_;  // h_states region: 33,554,432 floats
  float* Z0  = out;                        // reuse outputs region as Z0 scratch
  float* hsb = out + N_Y;                  // h_states [l][t][b][h]
  float* hff = out + N_Y + N_HS;           // h_final  [l][b][h]

  __half2* wp = (__half2*)d_ws;            // 5 * 32768 half2 = 640 KB
  __half2* Wp_xh0 = wp + 0*32768;
  __half2* Wp_hh0 = wp + 1*32768;
  __half2* Wp_xh1 = wp + 2*32768;
  __half2* Wp_hh1 = wp + 3*32768;
  __half2* Wp_hy  = wp + 4*32768;

  pack_w<<<128,256,0,stream>>>(Wxh0, Wp_xh0);
  pack_w<<<128,256,0,stream>>>(Whh0, Wp_hh0);
  pack_w<<<128,256,0,stream>>>(Wxh1, Wp_xh1);
  pack_w<<<128,256,0,stream>>>(Whh1, Wp_hh1);
  pack_w<<<128,256,0,stream>>>(Why,  Wp_hy);

  // Phase A: Z0 = x @ W_xh0 + b_h0   (rows r = b*S+t)
  gemm256<<<2048,256,0,stream>>>(x, Wp_xh0, bh0, Z0, 0);
  // Phase B: sequential scan (writes h_states and h_final; consumes Z0)
  rnn_seq<<<32,256,0,stream>>>(Wp_hh0, Wp_xh1, Wp_hh1, hprev, bh1, Z0, hsb, hff);
  // Phase C: outputs = h_states[1] @ W_hy + b_y  (overwrites Z0 region)
  gemm256<<<2048,256,0,stream>>>(hsb + (size_t)S_*B_*H_, Wp_hy, by, out, 1);
}

// Round 2
// 6742.805 us; speedup vs baseline: 1.2456x; 1.2456x over previous
//
#include <hip/hip_runtime.h>
#include <hip/hip_fp16.h>

#define B_ 32
#define S_ 2048
#define H_ 256

union UH { unsigned int u; __half2 h; };
__device__ __forceinline__ __half2 u2h(unsigned int u){ UH x; x.u = u; return x.h; }

__device__ __forceinline__ float fast_tanh(float x){
  // tanh(x) = 1 - 2/(exp(2x)+1); exact at +-inf, ~1e-7 rel err elsewhere
  float e = __expf(2.0f*x);
  return 1.0f - 2.0f/(e + 1.0f);
}

__device__ __forceinline__ float hsum8(__half2 a, __half2 b, __half2 c, __half2 d){
  float2 fa = __half22float2(a), fb = __half22float2(b);
  float2 fc = __half22float2(c), fd = __half22float2(d);
  return ((fa.x+fa.y)+(fb.x+fb.y)) + ((fc.x+fc.y)+(fd.x+fd.y));
}

// Pack fp32 [256][256] (k-major) into half2 [k2][j] with pair = (W[2k2][j], W[2k2+1][j])
__global__ void pack_w(const float* __restrict__ W, __half2* __restrict__ Wp){
  int idx = blockIdx.x*256 + threadIdx.x;        // 0..32767
  int k2 = idx >> 8, j = idx & 255;
  Wp[idx] = __floats2half2_rn(W[(2*k2)*256 + j], W[(2*k2+1)*256 + j]);
}

// Generic (M x 256) @ (256 x 256) + bias, rows r0..r0+31 per block.
// mode 0: Out[r*256+j]      (phase A: Z0[b][t][j], r = b*S+t)
// mode 1: Out[(b*S+t)*256+j] with r = t*32+b  (phase C: outputs from h_states[1] rows)
__global__ __launch_bounds__(256) void gemm256(
    const float* __restrict__ X, const __half2* __restrict__ Wp,
    const float* __restrict__ bias, float* __restrict__ Out, int mode)
{
  __shared__ __align__(16) __half2 xsh[32][128];
  const int j = threadIdx.x;
  const size_t r0 = (size_t)blockIdx.x * 32;

  for (int i = j; i < 32*128; i += 256){
    int rr = i >> 7, k2 = i & 127;
    const float* xs = X + (r0 + rr)*256 + 2*k2;
    xsh[rr][k2] = __floats2half2_rn(xs[0], xs[1]);
  }
  __half2 acc[32];
  #pragma unroll
  for (int r=0;r<32;r++) acc[r] = __floats2half2_rn(0.f,0.f);
  __syncthreads();

  for (int kc=0;kc<32;kc++){
    __half2 w0 = Wp[(kc*4+0)*256 + j];
    __half2 w1 = Wp[(kc*4+1)*256 + j];
    __half2 w2 = Wp[(kc*4+2)*256 + j];
    __half2 w3 = Wp[(kc*4+3)*256 + j];
    #pragma unroll
    for (int r=0;r<32;r++){
      uint4 xv = *reinterpret_cast<const uint4*>(&xsh[r][kc*4]);
      __half2 t0 = __hfma2(u2h(xv.x), w0, acc[r]);
      t0 = __hfma2(u2h(xv.y), w1, t0);
      t0 = __hfma2(u2h(xv.z), w2, t0);
      acc[r] = __hfma2(u2h(xv.w), w3, t0);
    }
  }
  float bj = bias[j];
  if (mode == 0){
    #pragma unroll
    for (int r=0;r<32;r++){
      float2 f = __half22float2(acc[r]);
      Out[(r0 + r)*256 + j] = bj + f.x + f.y;
    }
  } else {
    #pragma unroll
    for (int r=0;r<32;r++){
      size_t rr = r0 + r;
      size_t tt = rr >> 5, bb = rr & 31;
      float2 f = __half22float2(acc[r]);
      Out[(bb*(size_t)S_ + tt)*256 + j] = bj + f.x + f.y;
    }
  }
}

// Sequential scan: one workgroup per sample, 512 threads.
// Thread tid = j*2 + s: column j in [0,256), k-slice s in {0,1} (128 k each).
// Per-thread weights: 3 matrices x 64 half2 = 192 VGPRs (fits the 256-VGPR
// budget at 2 waves/SIMD; round-1's 384-reg layout spilled to scratch).
__global__ __launch_bounds__(512, 1) void rnn_seq(
    const __half2* __restrict__ Wp_hh0, const __half2* __restrict__ Wp_xh1,
    const __half2* __restrict__ Wp_hh1, const float* __restrict__ hprev,
    const float* __restrict__ b1, const float* __restrict__ Z0,
    float* __restrict__ hsbase, float* __restrict__ hf)
{
  const int b = blockIdx.x;
  const int tid = threadIdx.x;
  const int j = tid >> 1;          // column
  const int s = tid & 1;           // k-slice
  __shared__ __align__(16) __half hA[2][256];
  __shared__ __align__(16) __half hB[2][256];

  // Per-thread weight slices: w[c] covers k = 128*s + 2c, 2c+1
  __half2 w0[64], w1[64], w2[64];
  const int kbase = 64 * s;        // in half2 units
  #pragma unroll
  for (int c=0;c<64;c++){
    w0[c] = Wp_hh0[(kbase + c)*256 + j];
    w1[c] = Wp_xh1[(kbase + c)*256 + j];
    w2[c] = Wp_hh1[(kbase + c)*256 + j];
  }
  const float b1j = b1[j];
  if (s == 0){
    hA[0][j] = __float2half(hprev[b*256 + j]);
    hB[0][j] = __float2half(hprev[B_*H_ + b*256 + j]);
  }

  const float* zp = Z0 + (size_t)b*S_*H_ + j;
  float zcur = (s == 0) ? zp[0] : 0.f;
  float* hs0 = hsbase + (size_t)b*H_ + j;
  float* hs1 = hsbase + (size_t)S_*B_*H_ + (size_t)b*H_ + j;
  __syncthreads();

  int cur = 0;
  float h0n = 0.f, h1n = 0.f;
  for (int t=0; t<S_; t++){
    // prefetch next step's z (even lanes only; hidden behind this step's math)
    float znext = 0.f;
    if (s == 0) znext = zp[(size_t)(t+1 < S_ ? t+1 : t)*H_];

    // ---- phase 0: pa = h0_prev . W_hh0[:,j] (slice s); pc = h1_prev . W_hh1[:,j] (slice s)
    __half2 a0 = __floats2half2_rn(0.f,0.f), a1=a0, a2=a0, a3=a0;
    __half2 c0 = a0, c1=a0, c2=a0, c3=a0;
    {
      const uint4* hva = reinterpret_cast<const uint4*>(&hA[cur][128*s]);
      const uint4* hvb = reinterpret_cast<const uint4*>(&hB[cur][128*s]);
      #pragma unroll
      for (int c=0;c<16;c++){
        uint4 xa = hva[c];
        a0 = __hfma2(u2h(xa.x), w0[4*c+0], a0);
        a1 = __hfma2(u2h(xa.y), w0[4*c+1], a1);
        a2 = __hfma2(u2h(xa.z), w0[4*c+2], a2);
        a3 = __hfma2(u2h(xa.w), w0[4*c+3], a3);
        uint4 xb = hvb[c];
        c0 = __hfma2(u2h(xb.x), w2[4*c+0], c0);
        c1 = __hfma2(u2h(xb.y), w2[4*c+1], c1);
        c2 = __hfma2(u2h(xb.z), w2[4*c+2], c2);
        c3 = __hfma2(u2h(xb.w), w2[4*c+3], c3);
      }
    }
    float pa = hsum8(a0,a1,a2,a3);
    pa += __shfl_xor(pa, 1);
    if (s == 0){
      h0n = fast_tanh(zcur + pa);
      hs0[(size_t)t*B_*H_] = h0n;
      hA[cur^1][j] = __float2half(h0n);
    }
    __syncthreads();

    // ---- phase 1: pb = h0_new . W_xh1[:,j] (slice s) + pc
    __half2 d0 = __floats2half2_rn(0.f,0.f), d1=d0, d2=d0, d3=d0;
    {
      const uint4* hvn = reinterpret_cast<const uint4*>(&hA[cur^1][128*s]);
      #pragma unroll
      for (int c=0;c<16;c++){
        uint4 xn = hvn[c];
        d0 = __hfma2(u2h(xn.x), w1[4*c+0], d0);
        d1 = __hfma2(u2h(xn.y), w1[4*c+1], d1);
        d2 = __hfma2(u2h(xn.z), w1[4*c+2], d2);
        d3 = __hfma2(u2h(xn.w), w1[4*c+3], d3);
      }
    }
    float pb = hsum8(d0,d1,d2,d3) + hsum8(c0,c1,c2,c3);
    pb += __shfl_xor(pb, 1);
    if (s == 0){
      h1n = fast_tanh(b1j + pb);
      hs1[(size_t)t*B_*H_] = h1n;
      hB[cur^1][j] = __float2half(h1n);
    }
    zcur = znext;
    __syncthreads();
    cur ^= 1;
  }
  if (s == 0){
    hf[(size_t)b*H_ + j] = h0n;
    hf[(size_t)B_*H_ + (size_t)b*H_ + j] = h1n;
  }
}

extern "C" void kernel_launch(void* const* d_in, const int* in_sizes, int n_in,
                              void* d_out, int out_size, void* d_ws, size_t ws_size,
                              hipStream_t stream)
{
  const float* x     = (const float*)d_in[0];
  const float* hprev = (const float*)d_in[1];
  const float* Wxh0  = (const float*)d_in[2];
  const float* Whh0  = (const float*)d_in[3];
  const float* bh0   = (const float*)d_in[4];
  const float* Wxh1  = (const float*)d_in[5];
  const float* Whh1  = (const float*)d_in[6];
  const float* bh1   = (const float*)d_in[7];
  const float* Why   = (const float*)d_in[8];
  const float* by    = (const float*)d_in[9];
  float* out = (float*)d_out;

  const size_t N_Y  = (size_t)B_*S_*H_;    // outputs region: 16,777,216 floats
  const size_t N_HS = (size_t)2*S_*B_*H_;  // h_states region: 33,554,432 floats
  float* Z0  = out;                        // reuse outputs region as Z0 scratch
  float* hsb = out + N_Y;                  // h_states [l][t][b][h]
  float* hff = out + N_Y + N_HS;           // h_final  [l][b][h]

  __half2* wp = (__half2*)d_ws;            // 5 * 32768 half2 = 640 KB
  __half2* Wp_xh0 = wp + 0*32768;
  __half2* Wp_hh0 = wp + 1*32768;
  __half2* Wp_xh1 = wp + 2*32768;
  __half2* Wp_hh1 = wp + 3*32768;
  __half2* Wp_hy  = wp + 4*32768;

  pack_w<<<128,256,0,stream>>>(Wxh0, Wp_xh0);
  pack_w<<<128,256,0,stream>>>(Whh0, Wp_hh0);
  pack_w<<<128,256,0,stream>>>(Wxh1, Wp_xh1);
  pack_w<<<128,256,0,stream>>>(Whh1, Wp_hh1);
  pack_w<<<128,256,0,stream>>>(Why,  Wp_hy);

  // Phase A: Z0 = x @ W_xh0 + b_h0   (rows r = b*S+t)
  gemm256<<<2048,256,0,stream>>>(x, Wp_xh0, bh0, Z0, 0);
  // Phase B: sequential scan (writes h_states and h_final; consumes Z0)
  rnn_seq<<<32,512,0,stream>>>(Wp_hh0, Wp_xh1, Wp_hh1, hprev, bh1, Z0, hsb, hff);
  // Phase C: outputs = h_states[1] @ W_hy + b_y  (overwrites Z0 region)
  gemm256<<<2048,256,0,stream>>>(hsb + (size_t)S_*B_*H_, Wp_hy, by, out, 1);
}

// Round 3
// 5429.321 us; speedup vs baseline: 1.5469x; 1.2419x over previous
//
#include <hip/hip_runtime.h>
#include <hip/hip_fp16.h>

#define B_ 32
#define S_ 2048
#define H_ 256

union UH { unsigned int u; __half2 h; };
__device__ __forceinline__ __half2 u2h(unsigned int u){ UH x; x.u = u; return x.h; }
__device__ __forceinline__ unsigned int h2u(__half2 h){ UH x; x.h = h; return x.u; }

__device__ __forceinline__ float fast_tanh(float x){
  // tanh(x) = 1 - 2/(exp(2x)+1); exact at +-inf
  float e = __expf(2.0f*x);
  return 1.0f - 2.0f/(e + 1.0f);
}

// Pack fp32 [256][256] (k-major) into half2 [k2][j] with pair = (W[2k2][j], W[2k2+1][j])
__global__ void pack_w(const float* __restrict__ W, __half2* __restrict__ Wp){
  int idx = blockIdx.x*256 + threadIdx.x;        // 0..32767
  int k2 = idx >> 8, j = idx & 255;
  Wp[idx] = __floats2half2_rn(W[(2*k2)*256 + j], W[(2*k2+1)*256 + j]);
}

// Generic (M x 256) @ (256 x 256) + bias, rows r0..r0+31 per block.
// mode 0: Out[r*256+j]      (phase A: Z0[b][t][j], r = b*S+t)
// mode 1: Out[(b*S+t)*256+j] with r = t*32+b  (phase C)
__global__ __launch_bounds__(256) void gemm256(
    const float* __restrict__ X, const __half2* __restrict__ Wp,
    const float* __restrict__ bias, float* __restrict__ Out, int mode)
{
  __shared__ __align__(16) __half2 xsh[32][128];
  const int j = threadIdx.x;
  const size_t r0 = (size_t)blockIdx.x * 32;

  for (int i = j; i < 32*128; i += 256){
    int rr = i >> 7, k2 = i & 127;
    const float* xs = X + (r0 + rr)*256 + 2*k2;
    xsh[rr][k2] = __floats2half2_rn(xs[0], xs[1]);
  }
  __half2 acc[32];
  #pragma unroll
  for (int r=0;r<32;r++) acc[r] = __floats2half2_rn(0.f,0.f);
  __syncthreads();

  for (int kc=0;kc<32;kc++){
    __half2 w0 = Wp[(kc*4+0)*256 + j];
    __half2 w1 = Wp[(kc*4+1)*256 + j];
    __half2 w2 = Wp[(kc*4+2)*256 + j];
    __half2 w3 = Wp[(kc*4+3)*256 + j];
    #pragma unroll
    for (int r=0;r<32;r++){
      uint4 xv = *reinterpret_cast<const uint4*>(&xsh[r][kc*4]);
      __half2 t0 = __hfma2(u2h(xv.x), w0, acc[r]);
      t0 = __hfma2(u2h(xv.y), w1, t0);
      t0 = __hfma2(u2h(xv.z), w2, t0);
      acc[r] = __hfma2(u2h(xv.w), w3, t0);
    }
  }
  float bj = bias[j];
  if (mode == 0){
    #pragma unroll
    for (int r=0;r<32;r++){
      float2 f = __half22float2(acc[r]);
      Out[(r0 + r)*256 + j] = bj + f.x + f.y;
    }
  } else {
    #pragma unroll
    for (int r=0;r<32;r++){
      size_t rr = r0 + r;
      size_t tt = rr >> 5, bb = rr & 31;
      float2 f = __half22float2(acc[r]);
      Out[(bb*(size_t)S_ + tt)*256 + j] = bj + f.x + f.y;
    }
  }
}

// ---------------------------------------------------------------------------
// Sequential scan v3. One block per sample, 512 threads = 8 waves, pinned at
// 2 waves/SIMD (256-VGPR budget) via amdgpu_waves_per_eu(2,2).
// Thread (cg, kt): cg = tid>>3 owns 4 columns [4cg..4cg+4); kt = tid&7 owns a
// 32-element k-slice. Weights: 3 mats x 4 cols x 16 half2 = 192 VGPRs/thread.
// Each LDS h-element read feeds 4 columns -> 96 KB/step LDS (vs 384 KB in v2).
// Bank swizzle: k-thread kt reads uint4 block (c ^ (kt>>1)) at timeslot c;
// weight registers are permuted identically at load time. The 8 distinct
// addresses per timeslot then cover all 8 LDS bank-quads -> conflict-free.
// ---------------------------------------------------------------------------
#define RNN_STEP(CA, CB, NA, NB, ZIN, TT)                                      \
  {                                                                            \
    const __half2 z2 = __floats2half2_rn(0.f,0.f);                             \
    __half2 a[4] = {z2,z2,z2,z2};                                              \
    _Pragma("unroll")                                                          \
    for (int c=0;c<4;c++){                                                     \
      uint4 xa = *(const uint4*)(ldsb + (CA)*512 + offc[c]);                   \
      uint4 xb = *(const uint4*)(ldsb + (CB)*512 + offc[c]);                   \
      unsigned int xs[4]={xa.x,xa.y,xa.z,xa.w};                                \
      unsigned int ys[4]={xb.x,xb.y,xb.z,xb.w};                                \
      _Pragma("unroll")                                                        \
      for (int q=0;q<4;q++){                                                   \
        _Pragma("unroll")                                                      \
        for (int col=0;col<4;col++){                                           \
          a[col]  = __hfma2(u2h(xs[q]), w0[(c*4+q)*4+col], a[col]);            \
          cc[col] = __hfma2(u2h(ys[q]), w2[(c*4+q)*4+col], cc[col]);           \
        }                                                                      \
      }                                                                        \
    }                                                                          \
    float pa[4];                                                               \
    _Pragma("unroll")                                                          \
    for (int col=0;col<4;col++){                                               \
      float2 f=__half22float2(a[col]); pa[col]=f.x+f.y;                        \
      pa[col] += __shfl_xor(pa[col],1);                                        \
      pa[col] += __shfl_xor(pa[col],2);                                        \
      pa[col] += __shfl_xor(pa[col],4);                                        \
    }                                                                          \
    float h0v0=fast_tanh((ZIN).x+pa[0]), h0v1=fast_tanh((ZIN).y+pa[1]);        \
    float h0v2=fast_tanh((ZIN).z+pa[2]), h0v3=fast_tanh((ZIN).w+pa[3]);        \
    if (kt==0){                                                                \
      uint2 pk; pk.x=h2u(__floats2half2_rn(h0v0,h0v1));                        \
      pk.y=h2u(__floats2half2_rn(h0v2,h0v3));                                  \
      *(uint2*)(ldsb + (NA)*512 + 8*cg) = pk;                                  \
      *(float4*)(hs0p + (size_t)(TT)*(B_*H_)) = make_float4(h0v0,h0v1,h0v2,h0v3); \
    }                                                                          \
    __syncthreads();                                                           \
    __half2 d[4] = {z2,z2,z2,z2};                                              \
    _Pragma("unroll")                                                          \
    for (int c=0;c<4;c++){                                                     \
      uint4 xn = *(const uint4*)(ldsb + (NA)*512 + offc[c]);                   \
      unsigned int xs[4]={xn.x,xn.y,xn.z,xn.w};                                \
      _Pragma("unroll")                                                        \
      for (int q=0;q<4;q++)                                                    \
        _Pragma("unroll")                                                      \
        for (int col=0;col<4;col++)                                            \
          d[col] = __hfma2(u2h(xs[q]), w1[(c*4+q)*4+col], d[col]);             \
    }                                                                          \
    float pb[4];                                                               \
    _Pragma("unroll")                                                          \
    for (int col=0;col<4;col++){                                               \
      float2 f=__half22float2(d[col]); float2 g=__half22float2(cc[col]);       \
      pb[col]=(f.x+f.y)+(g.x+g.y);                                             \
      pb[col] += __shfl_xor(pb[col],1);                                        \
      pb[col] += __shfl_xor(pb[col],2);                                        \
      pb[col] += __shfl_xor(pb[col],4);                                        \
      cc[col] = z2;                                                            \
    }                                                                          \
    float h1v0=fast_tanh(b1v.x+pb[0]), h1v1=fast_tanh(b1v.y+pb[1]);            \
    float h1v2=fast_tanh(b1v.z+pb[2]), h1v3=fast_tanh(b1v.w+pb[3]);            \
    if (kt==0){                                                                \
      uint2 pk; pk.x=h2u(__floats2half2_rn(h1v0,h1v1));                        \
      pk.y=h2u(__floats2half2_rn(h1v2,h1v3));                                  \
      *(uint2*)(ldsb + (NB)*512 + 8*cg) = pk;                                  \
      *(float4*)(hs1p + (size_t)(TT)*(B_*H_)) = make_float4(h1v0,h1v1,h1v2,h1v3); \
    }                                                                          \
    __syncthreads();                                                           \
  }

__global__ __attribute__((amdgpu_flat_work_group_size(512,512), amdgpu_waves_per_eu(2,2)))
void rnn_seq(const __half2* __restrict__ Wp_hh0, const __half2* __restrict__ Wp_xh1,
             const __half2* __restrict__ Wp_hh1, const float* __restrict__ hprev,
             const float* __restrict__ b1, const float* __restrict__ Z0,
             float* __restrict__ hsbase, float* __restrict__ hf)
{
  const int b = blockIdx.x, tid = threadIdx.x;
  const int kt = tid & 7;          // k-thread within column group
  const int cg = tid >> 3;         // column group (4 cols each)
  const int key = kt >> 1;         // bank-swizzle key
  // LDS rows (512 B each): 0=hA buf0, 1=hA buf1, 2=hB buf0, 3=hB buf1
  __shared__ __align__(16) __half lds[4][256];
  char* ldsb = (char*)&lds[0][0];

  // Weight registers, permuted so register block c matches LDS read block c^key.
  __half2 w0[64], w1[64], w2[64];
  {
    const int colb = 4*cg;
    #pragma unroll
    for (int c=0;c<4;c++){
      #pragma unroll
      for (int q=0;q<4;q++){
        const int kh = kt*16 + ((c^key)*4 + q);   // half2 k-index
        #pragma unroll
        for (int col=0;col<4;col++){
          const int r = (c*4+q)*4+col;
          w0[r] = Wp_hh0[kh*256 + colb + col];
          w1[r] = Wp_xh1[kh*256 + colb + col];
          w2[r] = Wp_hh1[kh*256 + colb + col];
        }
      }
    }
  }
  int offc[4];
  #pragma unroll
  for (int c=0;c<4;c++) offc[c] = kt*64 + ((c^key)<<4);

  const float4 b1v = *(const float4*)(b1 + 4*cg);
  const float4* zq = (const float4*)(Z0 + (size_t)b*S_*H_) + cg;   // stride 64/row
  float* hs0p = hsbase + (size_t)b*H_ + 4*cg;
  float* hs1p = hsbase + (size_t)S_*B_*H_ + (size_t)b*H_ + 4*cg;

  if (kt==0){
    float4 h0i = *(const float4*)(hprev + b*H_ + 4*cg);
    float4 h1i = *(const float4*)(hprev + B_*H_ + b*H_ + 4*cg);
    uint2 p0, p1;
    p0.x = h2u(__floats2half2_rn(h0i.x,h0i.y)); p0.y = h2u(__floats2half2_rn(h0i.z,h0i.w));
    p1.x = h2u(__floats2half2_rn(h1i.x,h1i.y)); p1.y = h2u(__floats2half2_rn(h1i.z,h1i.w));
    *(uint2*)(ldsb + 0*512 + 8*cg) = p0;
    *(uint2*)(ldsb + 2*512 + 8*cg) = p1;
  }
  __half2 cc[4];
  #pragma unroll
  for (int col=0;col<4;col++) cc[col] = __floats2half2_rn(0.f,0.f);
  float4 zcur = zq[0];
  __syncthreads();

  #pragma unroll 1
  for (int t=0; t<S_; t+=2){
    float4 znext = zq[(size_t)(t+1)*64];
    RNN_STEP(0, 2, 1, 3, zcur, t)            // even sub-step: A 0->1, B 2->3
    int tpre = (t+2 < S_) ? (t+2) : 0;       // harmless dummy on last iter
    float4 znn = zq[(size_t)tpre*64];
    RNN_STEP(1, 3, 0, 2, znext, t+1)         // odd sub-step:  A 1->0, B 3->2
    zcur = znn;
  }

  // h_final: last h0/h1 are in LDS rows 0 and 2 (written by odd sub-step t=2047).
  if (kt==0){
    uint2 u0 = *(const uint2*)(ldsb + 0*512 + 8*cg);
    uint2 u1 = *(const uint2*)(ldsb + 2*512 + 8*cg);
    float2 f0 = __half22float2(u2h(u0.x)), f1 = __half22float2(u2h(u0.y));
    float2 g0 = __half22float2(u2h(u1.x)), g1 = __half22float2(u2h(u1.y));
    *(float4*)(hf + b*H_ + 4*cg)          = make_float4(f0.x,f0.y,f1.x,f1.y);
    *(float4*)(hf + B_*H_ + b*H_ + 4*cg)  = make_float4(g0.x,g0.y,g1.x,g1.y);
  }
}

extern "C" void kernel_launch(void* const* d_in, const int* in_sizes, int n_in,
                              void* d_out, int out_size, void* d_ws, size_t ws_size,
                              hipStream_t stream)
{
  const float* x     = (const float*)d_in[0];
  const float* hprev = (const float*)d_in[1];
  const float* Wxh0  = (const float*)d_in[2];
  const float* Whh0  = (const float*)d_in[3];
  const float* bh0   = (const float*)d_in[4];
  const float* Wxh1  = (const float*)d_in[5];
  const float* Whh1  = (const float*)d_in[6];
  const float* bh1   = (const float*)d_in[7];
  const float* Why   = (const float*)d_in[8];
  const float* by    = (const float*)d_in[9];
  float* out = (float*)d_out;

  const size_t N_Y  = (size_t)B_*S_*H_;    // outputs region
  const size_t N_HS = (size_t)2*S_*B_*H_;  // h_states region
  float* Z0  = out;                        // reuse outputs region as Z0 scratch
  float* hsb = out + N_Y;                  // h_states [l][t][b][h]
  float* hff = out + N_Y + N_HS;           // h_final  [l][b][h]

  __half2* wp = (__half2*)d_ws;            // 5 * 32768 half2 = 640 KB
  __half2* Wp_xh0 = wp + 0*32768;
  __half2* Wp_hh0 = wp + 1*32768;
  __half2* Wp_xh1 = wp + 2*32768;
  __half2* Wp_hh1 = wp + 3*32768;
  __half2* Wp_hy  = wp + 4*32768;

  pack_w<<<128,256,0,stream>>>(Wxh0, Wp_xh0);
  pack_w<<<128,256,0,stream>>>(Whh0, Wp_hh0);
  pack_w<<<128,256,0,stream>>>(Wxh1, Wp_xh1);
  pack_w<<<128,256,0,stream>>>(Whh1, Wp_hh1);
  pack_w<<<128,256,0,stream>>>(Why,  Wp_hy);

  // Phase A: Z0 = x @ W_xh0 + b_h0
  gemm256<<<2048,256,0,stream>>>(x, Wp_xh0, bh0, Z0, 0);
  // Phase B: sequential scan
  rnn_seq<<<32,512,0,stream>>>(Wp_hh0, Wp_xh1, Wp_hh1, hprev, bh1, Z0, hsb, hff);
  // Phase C: outputs = h_states[1] @ W_hy + b_y
  gemm256<<<2048,256,0,stream>>>(hsb + (size_t)S_*B_*H_, Wp_hy, by, out, 1);
}

// Round 4
// 5419.950 us; speedup vs baseline: 1.5496x; 1.0017x over previous
//
#include <hip/hip_runtime.h>
#include <hip/hip_fp16.h>

#define B_ 32
#define S_ 2048
#define H_ 256

union UH { unsigned int u; __half2 h; };
__device__ __forceinline__ __half2 u2h(unsigned int u){ UH x; x.u = u; return x.h; }
__device__ __forceinline__ unsigned int h2u(__half2 h){ UH x; x.h = h; return x.u; }

__device__ __forceinline__ float fast_tanh(float x){
  float e = __expf(2.0f*x);
  return 1.0f - 2.0f/(e + 1.0f);
}

// Pack fp32 [256][256] (k-major) into half2 [k2][j] with pair = (W[2k2][j], W[2k2+1][j])
__global__ void pack_w(const float* __restrict__ W, __half2* __restrict__ Wp){
  int idx = blockIdx.x*256 + threadIdx.x;        // 0..32767
  int k2 = idx >> 8, j = idx & 255;
  Wp[idx] = __floats2half2_rn(W[(2*k2)*256 + j], W[(2*k2+1)*256 + j]);
}

// Generic (M x 256) @ (256 x 256) + bias, rows r0..r0+31 per block.
__global__ __launch_bounds__(256) void gemm256(
    const float* __restrict__ X, const __half2* __restrict__ Wp,
    const float* __restrict__ bias, float* __restrict__ Out, int mode)
{
  __shared__ __align__(16) __half2 xsh[32][128];
  const int j = threadIdx.x;
  const size_t r0 = (size_t)blockIdx.x * 32;

  for (int i = j; i < 32*128; i += 256){
    int rr = i >> 7, k2 = i & 127;
    const float* xs = X + (r0 + rr)*256 + 2*k2;
    xsh[rr][k2] = __floats2half2_rn(xs[0], xs[1]);
  }
  __half2 acc[32];
  #pragma unroll
  for (int r=0;r<32;r++) acc[r] = __floats2half2_rn(0.f,0.f);
  __syncthreads();

  for (int kc=0;kc<32;kc++){
    __half2 w0 = Wp[(kc*4+0)*256 + j];
    __half2 w1 = Wp[(kc*4+1)*256 + j];
    __half2 w2 = Wp[(kc*4+2)*256 + j];
    __half2 w3 = Wp[(kc*4+3)*256 + j];
    #pragma unroll
    for (int r=0;r<32;r++){
      uint4 xv = *reinterpret_cast<const uint4*>(&xsh[r][kc*4]);
      __half2 t0 = __hfma2(u2h(xv.x), w0, acc[r]);
      t0 = __hfma2(u2h(xv.y), w1, t0);
      t0 = __hfma2(u2h(xv.z), w2, t0);
      acc[r] = __hfma2(u2h(xv.w), w3, t0);
    }
  }
  float bj = bias[j];
  if (mode == 0){
    #pragma unroll
    for (int r=0;r<32;r++){
      float2 f = __half22float2(acc[r]);
      Out[(r0 + r)*256 + j] = bj + f.x + f.y;
    }
  } else {
    #pragma unroll
    for (int r=0;r<32;r++){
      size_t rr = r0 + r;
      size_t tt = rr >> 5, bb = rr & 31;
      float2 f = __half22float2(acc[r]);
      Out[(bb*(size_t)S_ + tt)*256 + j] = bj + f.x + f.y;
    }
  }
}

// ---------------------------------------------------------------------------
// Sequential scan v4. Same decomposition as v3 (512 threads: cg=tid>>3 owns 4
// cols, kt=tid&7 owns a 32-k slice; XOR bank swizzle; conflict-free).
// NEW: weight values are pinned with asm volatile("" : "+v") after the initial
// load. This makes them non-rematerializable, so the compiler must keep all
// 192 weight dwords live in VGPRs across the t-loop instead of sinking the
// (loop-invariant) global loads back into the loop and re-streaming 384 KB
// per step from L2 (the round-3 bottleneck: VGPR=124, ~5900 cyc/step).
// ---------------------------------------------------------------------------
#define RNN_STEP(CA, CB, NA, NB, ZIN)                                          \
  {                                                                            \
    const __half2 z2 = __floats2half2_rn(0.f,0.f);                             \
    __half2 a[4] = {z2,z2,z2,z2};                                              \
    _Pragma("unroll")                                                          \
    for (int c=0;c<4;c++){                                                     \
      uint4 xa = *(const uint4*)(ldsb + (CA)*512 + offc[c]);                   \
      uint4 xb = *(const uint4*)(ldsb + (CB)*512 + offc[c]);                   \
      unsigned int xs[4]={xa.x,xa.y,xa.z,xa.w};                                \
      unsigned int ys[4]={xb.x,xb.y,xb.z,xb.w};                                \
      _Pragma("unroll")                                                        \
      for (int q=0;q<4;q++){                                                   \
        _Pragma("unroll")                                                      \
        for (int col=0;col<4;col++){                                           \
          a[col]  = __hfma2(u2h(xs[q]), u2h(w0u[(c*4+q)*4+col]), a[col]);      \
          cc[col] = __hfma2(u2h(ys[q]), u2h(w2u[(c*4+q)*4+col]), cc[col]);     \
        }                                                                      \
      }                                                                        \
    }                                                                          \
    float pa[4];                                                               \
    _Pragma("unroll")                                                          \
    for (int col=0;col<4;col++){                                               \
      float2 f=__half22float2(a[col]); pa[col]=f.x+f.y;                        \
      pa[col] += __shfl_xor(pa[col],1);                                        \
      pa[col] += __shfl_xor(pa[col],2);                                        \
      pa[col] += __shfl_xor(pa[col],4);                                        \
    }                                                                          \
    float h0v0=fast_tanh((ZIN).x+pa[0]), h0v1=fast_tanh((ZIN).y+pa[1]);        \
    float h0v2=fast_tanh((ZIN).z+pa[2]), h0v3=fast_tanh((ZIN).w+pa[3]);        \
    if (kt==0){                                                                \
      uint2 pk; pk.x=h2u(__floats2half2_rn(h0v0,h0v1));                        \
      pk.y=h2u(__floats2half2_rn(h0v2,h0v3));                                  \
      *(uint2*)(ldsb + (NA)*512 + 8*cg) = pk;                                  \
      *(float4*)hs0p = make_float4(h0v0,h0v1,h0v2,h0v3);                       \
    }                                                                          \
    __syncthreads();                                                           \
    __half2 d[4] = {z2,z2,z2,z2};                                              \
    _Pragma("unroll")                                                          \
    for (int c=0;c<4;c++){                                                     \
      uint4 xn = *(const uint4*)(ldsb + (NA)*512 + offc[c]);                   \
      unsigned int xs[4]={xn.x,xn.y,xn.z,xn.w};                                \
      _Pragma("unroll")                                                        \
      for (int q=0;q<4;q++)                                                    \
        _Pragma("unroll")                                                      \
        for (int col=0;col<4;col++)                                            \
          d[col] = __hfma2(u2h(xs[q]), u2h(w1u[(c*4+q)*4+col]), d[col]);       \
    }                                                                          \
    float pb[4];                                                               \
    _Pragma("unroll")                                                          \
    for (int col=0;col<4;col++){                                               \
      float2 f=__half22float2(d[col]); float2 g=__half22float2(cc[col]);       \
      pb[col]=(f.x+f.y)+(g.x+g.y);                                             \
      pb[col] += __shfl_xor(pb[col],1);                                        \
      pb[col] += __shfl_xor(pb[col],2);                                        \
      pb[col] += __shfl_xor(pb[col],4);                                        \
      cc[col] = z2;                                                            \
    }                                                                          \
    float h1v0=fast_tanh(b1v.x+pb[0]), h1v1=fast_tanh(b1v.y+pb[1]);            \
    float h1v2=fast_tanh(b1v.z+pb[2]), h1v3=fast_tanh(b1v.w+pb[3]);            \
    if (kt==0){                                                                \
      uint2 pk; pk.x=h2u(__floats2half2_rn(h1v0,h1v1));                        \
      pk.y=h2u(__floats2half2_rn(h1v2,h1v3));                                  \
      *(uint2*)(ldsb + (NB)*512 + 8*cg) = pk;                                  \
      *(float4*)hs1p = make_float4(h1v0,h1v1,h1v2,h1v3);                       \
    }                                                                          \
    hs0p += B_*H_; hs1p += B_*H_;                                              \
    __syncthreads();                                                           \
  }

__global__ __attribute__((amdgpu_flat_work_group_size(512,512), amdgpu_waves_per_eu(2,2)))
void rnn_seq(const __half2* __restrict__ Wp_hh0, const __half2* __restrict__ Wp_xh1,
             const __half2* __restrict__ Wp_hh1, const float* __restrict__ hprev,
             const float* __restrict__ b1, const float* __restrict__ Z0,
             float* __restrict__ hsbase, float* __restrict__ hf)
{
  const int b = blockIdx.x, tid = threadIdx.x;
  const int kt = tid & 7;          // k-thread within column group
  const int cg = tid >> 3;         // column group (4 cols each)
  const int key = kt >> 1;         // bank-swizzle key
  __shared__ __align__(16) __half lds[4][256];
  char* ldsb = (char*)&lds[0][0];

  // Weight registers (as dwords), permuted so reg block c matches LDS block c^key.
  unsigned int w0u[64], w1u[64], w2u[64];
  {
    const int colb = 4*cg;
    #pragma unroll
    for (int c=0;c<4;c++){
      #pragma unroll
      for (int q=0;q<4;q++){
        const int kh = kt*16 + ((c^key)*4 + q);   // half2 k-index
        #pragma unroll
        for (int col=0;col<4;col++){
          const int r = (c*4+q)*4+col;
          w0u[r] = h2u(Wp_hh0[kh*256 + colb + col]);
          w1u[r] = h2u(Wp_xh1[kh*256 + colb + col]);
          w2u[r] = h2u(Wp_hh1[kh*256 + colb + col]);
        }
      }
    }
  }
  // Pin every weight dword: the asm DEFINES the value, so it cannot be
  // rematerialized; the allocator must keep it live across the t-loop.
  #pragma unroll
  for (int r=0;r<64;r++){
    asm volatile("" : "+v"(w0u[r]));
    asm volatile("" : "+v"(w1u[r]));
    asm volatile("" : "+v"(w2u[r]));
  }

  int offc[4];
  #pragma unroll
  for (int c=0;c<4;c++) offc[c] = kt*64 + ((c^key)<<4);

  const float4 b1v = *(const float4*)(b1 + 4*cg);
  const float4* zqp = (const float4*)(Z0 + (size_t)b*S_*H_) + cg;   // advance 64/step
  float* hs0p = hsbase + (size_t)b*H_ + 4*cg;
  float* hs1p = hsbase + (size_t)S_*B_*H_ + (size_t)b*H_ + 4*cg;

  if (kt==0){
    float4 h0i = *(const float4*)(hprev + b*H_ + 4*cg);
    float4 h1i = *(const float4*)(hprev + B_*H_ + b*H_ + 4*cg);
    uint2 p0, p1;
    p0.x = h2u(__floats2half2_rn(h0i.x,h0i.y)); p0.y = h2u(__floats2half2_rn(h0i.z,h0i.w));
    p1.x = h2u(__floats2half2_rn(h1i.x,h1i.y)); p1.y = h2u(__floats2half2_rn(h1i.z,h1i.w));
    *(uint2*)(ldsb + 0*512 + 8*cg) = p0;
    *(uint2*)(ldsb + 2*512 + 8*cg) = p1;
  }
  __half2 cc[4];
  #pragma unroll
  for (int col=0;col<4;col++) cc[col] = __floats2half2_rn(0.f,0.f);
  float4 zcur = zqp[0];
  __syncthreads();

  #pragma unroll 1
  for (int t=0; t<S_; t+=2){
    float4 znext = zqp[64];
    RNN_STEP(0, 2, 1, 3, zcur)               // even sub-step: A 0->1, B 2->3
    float4 znn = (t+2 < S_) ? zqp[128] : zcur;
    RNN_STEP(1, 3, 0, 2, znext)              // odd sub-step:  A 1->0, B 3->2
    zcur = znn;
    zqp += 128;
  }

  // h_final: last h0/h1 are in LDS rows 0 and 2.
  if (kt==0){
    uint2 u0 = *(const uint2*)(ldsb + 0*512 + 8*cg);
    uint2 u1 = *(const uint2*)(ldsb + 2*512 + 8*cg);
    float2 f0 = __half22float2(u2h(u0.x)), f1 = __half22float2(u2h(u0.y));
    float2 g0 = __half22float2(u2h(u1.x)), g1 = __half22float2(u2h(u1.y));
    *(float4*)(hf + b*H_ + 4*cg)          = make_float4(f0.x,f0.y,f1.x,f1.y);
    *(float4*)(hf + B_*H_ + b*H_ + 4*cg)  = make_float4(g0.x,g0.y,g1.x,g1.y);
  }
}

extern "C" void kernel_launch(void* const* d_in, const int* in_sizes, int n_in,
                              void* d_out, int out_size, void* d_ws, size_t ws_size,
                              hipStream_t stream)
{
  const float* x     = (const float*)d_in[0];
  const float* hprev = (const float*)d_in[1];
  const float* Wxh0  = (const float*)d_in[2];
  const float* Whh0  = (const float*)d_in[3];
  const float* bh0   = (const float*)d_in[4];
  const float* Wxh1  = (const float*)d_in[5];
  const float* Whh1  = (const float*)d_in[6];
  const float* bh1   = (const float*)d_in[7];
  const float* Why   = (const float*)d_in[8];
  const float* by    = (const float*)d_in[9];
  float* out = (float*)d_out;

  const size_t N_Y  = (size_t)B_*S_*H_;    // outputs region
  const size_t N_HS = (size_t)2*S_*B_*H_;  // h_states region
  float* Z0  = out;                        // reuse outputs region as Z0 scratch
  float* hsb = out + N_Y;                  // h_states [l][t][b][h]
  float* hff = out + N_Y + N_HS;           // h_final  [l][b][h]

  __half2* wp = (__half2*)d_ws;            // 5 * 32768 half2 = 640 KB
  __half2* Wp_xh0 = wp + 0*32768;
  __half2* Wp_hh0 = wp + 1*32768;
  __half2* Wp_xh1 = wp + 2*32768;
  __half2* Wp_hh1 = wp + 3*32768;
  __half2* Wp_hy  = wp + 4*32768;

  pack_w<<<128,256,0,stream>>>(Wxh0, Wp_xh0);
  pack_w<<<128,256,0,stream>>>(Whh0, Wp_hh0);
  pack_w<<<128,256,0,stream>>>(Wxh1, Wp_xh1);
  pack_w<<<128,256,0,stream>>>(Whh1, Wp_hh1);
  pack_w<<<128,256,0,stream>>>(Why,  Wp_hy);

  // Phase A: Z0 = x @ W_xh0 + b_h0
  gemm256<<<2048,256,0,stream>>>(x, Wp_xh0, bh0, Z0, 0);
  // Phase B: sequential scan
  rnn_seq<<<32,512,0,stream>>>(Wp_hh0, Wp_xh1, Wp_hh1, hprev, bh1, Z0, hsb, hff);
  // Phase C: outputs = h_states[1] @ W_hy + b_y
  gemm256<<<2048,256,0,stream>>>(hsb + (size_t)S_*B_*H_, Wp_hy, by, out, 1);
}